// Round 1
// baseline (259.914 us; speedup 1.0000x reference)
//
#include <hip/hip_runtime.h>
#include <hip/hip_cooperative_groups.h>
#include <math.h>

// Problem constants (from reference setup_inputs): B=16, T=2048, D=512, K=3.
#define B_ 16
#define T_ 2048
#define D_ 512
#define NCHUNK_ (T_ / 64)   // 32 chunks of 64 t per batch row

namespace cg = cooperative_groups;

// ---------------------------------------------------------------------------
// Fused cooperative kernel: phase1 alphas -> grid.sync -> phase2 scan finish
// -> grid.sync -> phase3 gather. Grid = (32 chunks, 16 b), 512 blocks, all
// co-resident (2 blocks/CU guaranteed by __launch_bounds__(256,2)).
//
// Layout (verified R9): f32 outputs, [acoustic B*ML*D | token B | alphas B*T
// | fires B*T]; f32 inputs. ws: S f64 + fire_pos i32 + n_fires + chunk_sum.
// ---------------------------------------------------------------------------
__global__ __launch_bounds__(256, 2) void k_fused(
    const float* __restrict__ hidden,
    const float* __restrict__ conv_w,   // [D,1,3]
    const float* __restrict__ conv_b,   // [D]
    const float* __restrict__ lin_w,    // [1,D]
    const float* __restrict__ lin_b,    // [1]
    float*  __restrict__ acoustic,      // [B*ML*D] out chunk 0
    float*  __restrict__ token_out,     // [B]      out chunk 1
    float*  __restrict__ alphas_out,    // [B*T]    out chunk 2
    float*  __restrict__ fires_out,     // [B*T]    out chunk 3
    double* __restrict__ S,             // [B*T]    ws
    int*    __restrict__ fire_pos,      // [B*T]    ws (slot -> t)
    int*    __restrict__ n_fires,       // [B]      ws
    double* __restrict__ chunk_sum,     // [B*32]   ws
    int ML)
{
    cg::grid_group grid = cg::this_grid();

    const int c    = blockIdx.x;          // chunk index 0..31
    const int b    = blockIdx.y;
    const int wv   = threadIdx.x >> 6;
    const int lane = threadIdx.x & 63;
    const int t0   = c * 64 + wv * 16;
    const int d0   = lane * 8;

    __shared__ float salpha[64];          // this block's 64 alphas

    // ---- phase 1: alphas (sliding 3-row register window, 1-ahead prefetch) ----
    {
        float w0[8], w1[8], w2[8], cb[8], lw[8];
        #pragma unroll
        for (int i = 0; i < 8; ++i) {
            int d = d0 + i;
            w0[i] = conv_w[3 * d];
            w1[i] = conv_w[3 * d + 1];
            w2[i] = conv_w[3 * d + 2];
            cb[i] = conv_b[d];
            lw[i] = lin_w[d];
        }
        const float lb = lin_b[0];

        const float* rbase = hidden + (size_t)b * T_ * D_ + d0;
        auto loadrow = [&](int t, float* f) {
            const float4* p = (const float4*)(rbase + (size_t)t * D_);
            float4 x = p[0], y = p[1];
            f[0]=x.x; f[1]=x.y; f[2]=x.z; f[3]=x.w;
            f[4]=y.x; f[5]=y.y; f[6]=y.z; f[7]=y.w;
        };

        float hm[8], hc[8], hp[8], nx[8];
        if (t0 > 0) { loadrow(t0 - 1, hm); }
        else        { for (int i = 0; i < 8; ++i) hm[i] = 0.f; }
        loadrow(t0, hc);
        loadrow(t0 + 1, hp);          // t0+1 <= 2033 < T, always in range

        float* aout = alphas_out + (size_t)b * T_;
        #pragma unroll 4
        for (int j = 0; j < 16; ++j) {
            const int t = t0 + j;
            const int tn = t + 2;
            if (tn < T_) { loadrow(tn, nx); }
            else         { for (int i = 0; i < 8; ++i) nx[i] = 0.f; }

            float dot = 0.f;
            #pragma unroll
            for (int i = 0; i < 8; ++i) {
                float mem = fmaf(hm[i], w0[i],
                            fmaf(hc[i], w1[i],
                            fmaf(hp[i], w2[i], cb[i])));
                float o = mem + hc[i];
                o = o > 0.f ? o : 0.f;
                dot += o * lw[i];
            }
            #pragma unroll
            for (int off = 32; off > 0; off >>= 1) dot += __shfl_down(dot, off);
            if (lane == 0) {
                float av = 1.f / (1.f + expf(-(dot + lb)));
                aout[t] = av;
                salpha[wv * 16 + j] = av;
            }
            #pragma unroll
            for (int i = 0; i < 8; ++i) { hm[i] = hc[i]; hc[i] = hp[i]; hp[i] = nx[i]; }
        }
    }
    __syncthreads();

    // wave 0: fp64 inclusive scan of this chunk's 64 alphas; publish chunk sum.
    double a_j = 0.0, incl = 0.0;
    if (wv == 0) {
        a_j  = (double)salpha[lane];
        incl = a_j;
        #pragma unroll
        for (int off = 1; off < 64; off <<= 1) {
            double v = __shfl_up(incl, off);
            if (lane >= off) incl += v;
        }
        if (lane == 63) chunk_sum[b * NCHUNK_ + c] = incl;
    }

    grid.sync();

    // ---- phase 2: add chunk base, emit S / fires / fire_pos / token ----
    if (wv == 0) {
        double v = (lane < c) ? chunk_sum[b * NCHUNK_ + lane] : 0.0;
        #pragma unroll
        for (int off = 32; off > 0; off >>= 1) v += __shfl_down(v, off);
        const double base = __shfl(v, 0);   // exclusive prefix of chunks < c

        const int t     = c * 64 + lane;
        const size_t bt = (size_t)b * T_ + t;
        const double run  = base + incl;      // inclusive S_t
        const double excl = run - a_j;        // S_{t-1}
        const double fp   = floor(excl);
        S[bt] = run;
        fires_out[bt] = (float)(run - fp);                            // integ pre-reset
        if (run >= fp + 1.0)
            fire_pos[(size_t)b * T_ + (long long)fp] = t;             // closes slot fp
        if (c == NCHUNK_ - 1 && lane == 63) {
            n_fires[b]   = (int)floor(run);
            token_out[b] = (float)run;
        }
    }

    grid.sync();

    // ---- phase 3: gather. Two slots per block concurrently (half-block per
    // slot, float4/lane) to keep loads in flight at 2 blocks/CU. ----
    {
        const int nblk  = NCHUNK_ * B_;             // 512
        const int flat  = b * NCHUNK_ + c;
        const int total = ML * B_;
        const int half  = threadIdx.x >> 7;         // 0/1: which slot of the pair
        const int tq    = threadIdx.x & 127;        // float4 column index

        for (int u0 = flat * 2; u0 < total; u0 += nblk * 2) {
            const int u = u0 + half;
            if (u >= total) continue;
            const int gb = u / ML;
            const int s  = u - gb * ML;

            float4* dst = (float4*)(acoustic + ((size_t)gb * ML + s) * D_) + tq;
            int nf = n_fires[gb];
            if (nf > ML) nf = ML;
            if (s >= nf) { *dst = make_float4(0.f, 0.f, 0.f, 0.f); continue; }

            const size_t gbase = (size_t)gb * T_;
            const int t_end    = fire_pos[gbase + s];
            const int t_start  = (s == 0) ? 0 : fire_pos[gbase + s - 1];

            const double vlo = (double)s, vhi = (double)(s + 1);
            float a0 = 0.f, a1 = 0.f, a2 = 0.f, a3 = 0.f;
            double Sp = (t_start == 0) ? 0.0 : S[gbase + t_start - 1];
            const float4* hrow =
                (const float4*)(hidden + (gbase + (size_t)t_start) * D_) + tq;
            for (int t = t_start; t <= t_end; ++t, hrow += D_ / 4) {
                double St = S[gbase + t];
                double wd = fmin(St, vhi) - fmax(Sp, vlo);
                float w = wd > 0.0 ? (float)wd : 0.f;
                float4 hv = *hrow;
                a0 += w * hv.x; a1 += w * hv.y; a2 += w * hv.z; a3 += w * hv.w;
                Sp = St;
            }
            *dst = make_float4(a0, a1, a2, a3);
        }
    }
}

extern "C" void kernel_launch(void* const* d_in, const int* in_sizes, int n_in,
                              void* d_out, int out_size, void* d_ws, size_t ws_size,
                              hipStream_t stream) {
    (void)in_sizes; (void)n_in; (void)ws_size;
    const float* hidden = (const float*)d_in[0];
    const float* conv_w = (const float*)d_in[1];
    const float* conv_b = (const float*)d_in[2];
    const float* lin_w  = (const float*)d_in[3];
    const float* lin_b  = (const float*)d_in[4];

    const int B = B_, T = T_, D = D_;
    // f32-element layout: [acoustic B*ML*D | token B | alphas B*T | fires B*T]
    int ML = (out_size - (B + 2 * B * T)) / (B * D);
    if (ML < 1) ML = 1;

    float* out        = (float*)d_out;
    float* acoustic   = out;
    float* token_out  = out + (size_t)B * ML * D;
    float* alphas_out = token_out + B;
    float* fires_out  = alphas_out + (size_t)B * T;

    // ws: S f64 first (8B align), then fire_pos i32, n_fires i32, chunk_sum f64.
    double* S         = (double*)d_ws;                    // 256 KB
    int*    fire_pos  = (int*)(S + (size_t)B * T);        // 128 KB
    int*    n_fires   = fire_pos + (size_t)B * T;         // 64 B
    double* chunk_sum = (double*)(n_fires + B);           // 4 KB (8B-aligned: 384K+64)

    void* kargs[] = {
        (void*)&hidden, (void*)&conv_w, (void*)&conv_b, (void*)&lin_w, (void*)&lin_b,
        (void*)&acoustic, (void*)&token_out, (void*)&alphas_out, (void*)&fires_out,
        (void*)&S, (void*)&fire_pos, (void*)&n_fires, (void*)&chunk_sum, (void*)&ML
    };
    hipLaunchCooperativeKernel((const void*)k_fused, dim3(NCHUNK_, B),
                               dim3(256), kargs, 0, stream);
}

// Round 2
// 126.324 us; speedup vs baseline: 2.0575x; 2.0575x over previous
//
#include <hip/hip_runtime.h>
#include <math.h>

// Problem constants (from reference setup_inputs): B=16, T=2048, D=512, K=3.
#define B_ 16
#define T_ 2048
#define D_ 512

// ---------------------------------------------------------------------------
// Layout (verified R9): f32 outputs, [acoustic B*ML*D | token B | alphas B*T
// | fires B*T]; f32 inputs. ws: S f64 + fire_pos i32 + n_fires.
// Three plain launches (graph-capturable; cooperative launch added ~100us
// overhead in R1 and serialized the gather -- reverted).
// ---------------------------------------------------------------------------

// k1: alphas[b,t] = sigmoid(sum_d relu(conv3+res)*lin_w + lin_b).
// Grid (T/32, B) = 1024 blocks, 4 waves; each wave owns 8 t, lane owns 8 d.
// All 10 rows (t0-1 .. t0+8) loaded upfront -> 20 dwordx4 in flight per wave,
// single wait, then pure compute. Latency fully amortized (R1 post-mortem:
// depth-1 prefetch at 2 waves/SIMD stalled ~900cyc/row).
__global__ __launch_bounds__(256) void k_alphas(
    const float* __restrict__ hidden,
    const float* __restrict__ conv_w,   // [D,1,3]
    const float* __restrict__ conv_b,   // [D]
    const float* __restrict__ lin_w,    // [1,D]
    const float* __restrict__ lin_b,    // [1]
    float* __restrict__ alphas_out)     // [B*T] out chunk 2
{
    const int b    = blockIdx.y;
    const int wv   = threadIdx.x >> 6;
    const int lane = threadIdx.x & 63;
    const int t0   = blockIdx.x * 32 + wv * 8;
    const int d0   = lane * 8;

    float w0[8], w1[8], w2[8], cb[8], lw[8];
    #pragma unroll
    for (int i = 0; i < 8; ++i) {
        int d = d0 + i;
        w0[i] = conv_w[3 * d];
        w1[i] = conv_w[3 * d + 1];
        w2[i] = conv_w[3 * d + 2];
        cb[i] = conv_b[d];
        lw[i] = lin_w[d];
    }
    const float lb = lin_b[0];

    const float* rbase = hidden + (size_t)b * T_ * D_ + d0;

    // rows t0-1 .. t0+8 ; indices static after full unroll (no scratch).
    float r[10][8];
    #pragma unroll
    for (int k = 0; k < 10; ++k) {
        const int t = t0 - 1 + k;
        if (t >= 0 && t < T_) {           // wave-uniform guard
            const float4* p = (const float4*)(rbase + (size_t)t * D_);
            float4 x = p[0], y = p[1];
            r[k][0]=x.x; r[k][1]=x.y; r[k][2]=x.z; r[k][3]=x.w;
            r[k][4]=y.x; r[k][5]=y.y; r[k][6]=y.z; r[k][7]=y.w;
        } else {
            #pragma unroll
            for (int i = 0; i < 8; ++i) r[k][i] = 0.f;
        }
    }

    float* aout = alphas_out + (size_t)b * T_;
    #pragma unroll
    for (int j = 0; j < 8; ++j) {
        float dot = 0.f;
        #pragma unroll
        for (int i = 0; i < 8; ++i) {
            float mem = fmaf(r[j][i], w0[i],
                        fmaf(r[j+1][i], w1[i],
                        fmaf(r[j+2][i], w2[i], cb[i])));
            float o = mem + r[j+1][i];
            o = o > 0.f ? o : 0.f;
            dot += o * lw[i];
        }
        #pragma unroll
        for (int off = 32; off > 0; off >>= 1) dot += __shfl_down(dot, off);
        if (lane == 0) aout[t0 + j] = 1.f / (1.f + expf(-(dot + lb)));
    }
}

// k2: fp64 inclusive prefix sum per row; emits S, fire positions, fires,
// token. Wave-level shfl_up scan + single barrier (replaces R9's 16-barrier
// Hillis-Steele). Identical summation structure otherwise.
__global__ __launch_bounds__(256) void k_scan(
    const float* __restrict__ alphas_in,   // [B*T] (= out chunk 2)
    double* __restrict__ S,                // [B*T] ws
    int*    __restrict__ fire_pos,         // [B*T] ws (slot -> t)
    int*    __restrict__ n_fires,          // [B]   ws
    float*  __restrict__ fires_out,        // [B*T] out chunk 3
    float*  __restrict__ token_out)        // [B]   out chunk 1
{
    const int b = blockIdx.x, tid = threadIdx.x;
    const int wv = tid >> 6, lane = tid & 63;
    const size_t base = (size_t)b * T_;

    // 8 consecutive alphas per thread, two float4 loads.
    const float4* ap = (const float4*)(alphas_in + base + tid * 8);
    float4 a0 = ap[0], a1 = ap[1];
    double a[8];
    a[0]=a0.x; a[1]=a0.y; a[2]=a0.z; a[3]=a0.w;
    a[4]=a1.x; a[5]=a1.y; a[6]=a1.z; a[7]=a1.w;
    double tsum = 0.0;
    #pragma unroll
    for (int i = 0; i < 8; ++i) tsum += a[i];

    // wave inclusive scan of per-thread sums
    double incl = tsum;
    #pragma unroll
    for (int off = 1; off < 64; off <<= 1) {
        double v = __shfl_up(incl, off);
        if (lane >= off) incl += v;
    }
    __shared__ double wsum[4];
    if (lane == 63) wsum[wv] = incl;
    __syncthreads();
    double wbase = 0.0;
    #pragma unroll
    for (int w = 0; w < 3; ++w) if (w < wv) wbase += wsum[w];

    double run = wbase + incl - tsum;   // exclusive prefix of this thread's chunk

    #pragma unroll
    for (int i = 0; i < 8; ++i) {
        int t = tid * 8 + i;
        double Sp = run, fp = floor(Sp);
        run += a[i];
        S[base + t] = run;
        fires_out[base + t] = (float)(run - fp);                  // integ pre-reset
        if (run >= fp + 1.0) fire_pos[base + (long long)fp] = t;  // closes slot fp
    }
    if (tid == 255) {
        n_fires[b]   = (int)floor(run);
        token_out[b] = (float)run;
    }
}

// k3: acoustic[b,s,:] = sum_t w_t * hidden[b,t,:], w_t = overlap of
// [S_{t-1},S_t] with [s,s+1] clamped >=0; t in [fire_pos[s-1], fire_pos[s]].
// One block per (s,b); 128 threads (2 waves), float4 per thread -> 2x the
// independent blocks in flight vs 256-thread float2 version.
__global__ __launch_bounds__(128) void k_gather(
    const float*  __restrict__ hidden,
    const double* __restrict__ S,
    const int*    __restrict__ fire_pos,
    const int*    __restrict__ n_fires,
    float* __restrict__ acoustic, int ML)
{
    const int s = blockIdx.x, b = blockIdx.y;
    float4* dst = (float4*)(acoustic + ((size_t)b * ML + s) * D_) + threadIdx.x;

    int nf = n_fires[b];
    if (nf > ML) nf = ML;
    if (s >= nf) { *dst = make_float4(0.f, 0.f, 0.f, 0.f); return; }

    const size_t base = (size_t)b * T_;
    const int t_end   = fire_pos[base + s];
    const int t_start = (s == 0) ? 0 : fire_pos[base + s - 1];

    const double vlo = (double)s, vhi = (double)(s + 1);
    float a0 = 0.f, a1 = 0.f, a2 = 0.f, a3 = 0.f;
    double Sp = (t_start == 0) ? 0.0 : S[base + t_start - 1];
    const float4* hrow =
        (const float4*)(hidden + (base + (size_t)t_start) * D_) + threadIdx.x;
    for (int t = t_start; t <= t_end; ++t, hrow += D_ / 4) {
        double St = S[base + t];
        double wd = fmin(St, vhi) - fmax(Sp, vlo);
        float w = wd > 0.0 ? (float)wd : 0.f;
        float4 hv = *hrow;
        a0 += w * hv.x; a1 += w * hv.y; a2 += w * hv.z; a3 += w * hv.w;
        Sp = St;
    }
    *dst = make_float4(a0, a1, a2, a3);
}

extern "C" void kernel_launch(void* const* d_in, const int* in_sizes, int n_in,
                              void* d_out, int out_size, void* d_ws, size_t ws_size,
                              hipStream_t stream) {
    (void)in_sizes; (void)n_in; (void)ws_size;
    const float* hidden = (const float*)d_in[0];
    const float* conv_w = (const float*)d_in[1];
    const float* conv_b = (const float*)d_in[2];
    const float* lin_w  = (const float*)d_in[3];
    const float* lin_b  = (const float*)d_in[4];

    const int B = B_, T = T_, D = D_;
    // f32-element layout: [acoustic B*ML*D | token B | alphas B*T | fires B*T]
    int ML = (out_size - (B + 2 * B * T)) / (B * D);
    if (ML < 1) ML = 1;

    float* out        = (float*)d_out;
    float* acoustic   = out;
    float* token_out  = out + (size_t)B * ML * D;
    float* alphas_out = token_out + B;
    float* fires_out  = alphas_out + (size_t)B * T;

    // ws: S f64 first (8B align), then fire_pos i32, n_fires.
    double* S        = (double*)d_ws;                    // 256 KB
    int*    fire_pos = (int*)(S + (size_t)B * T);        // 128 KB
    int*    n_fires  = fire_pos + (size_t)B * T;         // 64 B

    k_alphas<<<dim3(T / 32, B), 256, 0, stream>>>(hidden, conv_w, conv_b,
                                                  lin_w, lin_b, alphas_out);
    k_scan<<<B, 256, 0, stream>>>(alphas_out, S, fire_pos, n_fires,
                                  fires_out, token_out);
    k_gather<<<dim3(ML, B), 128, 0, stream>>>(hidden, S, fire_pos, n_fires,
                                              acoustic, ML);
}